// Round 1
// baseline (7827.258 us; speedup 1.0000x reference)
//
#include <hip/hip_runtime.h>

typedef short short8 __attribute__((ext_vector_type(8)));
typedef float floatx4 __attribute__((ext_vector_type(4)));

#define DI __device__ __forceinline__

constexpr int Bn   = 32;          // batch
constexpr int HW   = 56;          // spatial H == W
constexpr int E    = 384;
constexpr int E3   = 1152;
constexpr int NHd  = 12;
constexpr int HD   = 32;
constexpr int SH   = 4;           // shift
constexpr int T    = 64;          // tokens per window (8x8)
constexpr int NWIN = Bn * 7 * 7;  // 1568 windows
constexpr int MROW = NWIN * T;    // 100352

constexpr int XW_LD = E + 8;      // 392  (bf16 elems; 784 B row: 4-bank rotation -> 2-way max)
constexpr int QK_LD = HD + 8;     // 40
constexpr int VT_LD = T + 8;      // 72
constexpr int P_LD  = T + 8;      // 72

DI unsigned short f2bf(float f) {
  unsigned int u = __builtin_bit_cast(unsigned int, f);
  u = u + 0x7FFFu + ((u >> 16) & 1u);   // round-to-nearest-even
  return (unsigned short)(u >> 16);
}

// ---------------- kernel 1: weights fp32 -> bf16 ----------------
__global__ void cast_weights(const float* __restrict__ wqkv,
                             const float* __restrict__ wout,
                             unsigned short* __restrict__ wqkv_bf,
                             unsigned short* __restrict__ wout_bf) {
  int i = blockIdx.x * 256 + threadIdx.x;
  const int n1 = E3 * E;            // 442368
  const int n2 = E * E;             // 147456
  if (i < n1) wqkv_bf[i] = f2bf(wqkv[i]);
  else if (i < n1 + n2) wout_bf[i - n1] = f2bf(wout[i - n1]);
}

// ---------------- kernel 2: per-window fused QKV + attention ----------------
// grid = 1568 blocks (one per window), 256 threads (4 waves)
__global__ __launch_bounds__(256, 2)
void win_attn(const float* __restrict__ x,
              const unsigned short* __restrict__ wqkv,   // [1152][384] bf16
              const float* __restrict__ bqkv,            // [1152]
              unsigned short* __restrict__ o_ws) {       // [100352][384] bf16
  __shared__ unsigned short xw[T * XW_LD];   // 50176 B
  __shared__ unsigned short qs[T * QK_LD];   //  5120 B
  __shared__ unsigned short ks[T * QK_LD];   //  5120 B
  __shared__ unsigned short vT[HD * VT_LD];  //  4608 B
  __shared__ unsigned short ps[T * P_LD];    //  9216 B

  const int tid  = threadIdx.x;
  const int wave = tid >> 6, lane = tid & 63;
  const int quad = lane >> 4, l16 = lane & 15;

  const int win  = blockIdx.x;
  const int b    = win / 49;
  const int wrem = win % 49;
  const int wi   = wrem / 7, wj = wrem % 7;

  // ---- stage x window -> bf16 LDS (fused roll + window partition) ----
  #pragma unroll
  for (int it = 0; it < 24; ++it) {
    int f   = tid + it * 256;        // 0..6143 over 64 rows x 96 float4
    int row = f / 96;
    int c4  = f % 96;
    int ti = row >> 3, tj = row & 7;
    int gi = (wi * 8 + ti + SH) % HW;
    int gj = (wj * 8 + tj + SH) % HW;
    const float4 v = *reinterpret_cast<const float4*>(
        x + (size_t)(b * 3136 + gi * 56 + gj) * E + c4 * 4);
    ushort4 hv;
    hv.x = f2bf(v.x); hv.y = f2bf(v.y); hv.z = f2bf(v.z); hv.w = f2bf(v.w);
    *reinterpret_cast<ushort4*>(&xw[row * XW_LD + c4 * 4]) = hv;
  }
  __syncthreads();

  const floatx4 zero4 = {0.f, 0.f, 0.f, 0.f};
  // n-tile assignment for the 64x96 QKV GEMM: wave0:{q0,q1} wave1:{k0,k1} wave2:{v0} wave3:{v1}
  const int nt0  = (wave == 0) ? 0 : (wave == 1) ? 2 : (wave == 2) ? 4 : 5;
  const int ncnt = (wave < 2) ? 2 : 1;

  for (int h = 0; h < NHd; ++h) {
    // ---- QKV GEMM: C[64 x 96] = xw[64x384] @ Wh[96x384]^T ----
    floatx4 acc[2][4];
    #pragma unroll
    for (int a = 0; a < 2; ++a)
      #pragma unroll
      for (int m = 0; m < 4; ++m) acc[a][m] = zero4;

    int gcol[2];
    for (int a = 0; a < ncnt; ++a) {
      int nt = nt0 + a;
      int g = (nt < 2) ? (h * HD + nt * 16)
            : (nt < 4) ? (E + h * HD + (nt - 2) * 16)
                       : (2 * E + h * HD + (nt - 4) * 16);
      gcol[a] = g + l16;
    }

    #pragma unroll
    for (int kk = 0; kk < 12; ++kk) {
      short8 bfr[2];
      for (int a = 0; a < ncnt; ++a)
        bfr[a] = *reinterpret_cast<const short8*>(
            wqkv + (size_t)gcol[a] * E + kk * 32 + quad * 8);
      #pragma unroll
      for (int m = 0; m < 4; ++m) {
        short8 afr = *reinterpret_cast<const short8*>(
            &xw[(m * 16 + l16) * XW_LD + kk * 32 + quad * 8]);
        for (int a = 0; a < ncnt; ++a)
          acc[a][m] = __builtin_amdgcn_mfma_f32_16x16x32_bf16(afr, bfr[a], acc[a][m], 0, 0, 0);
      }
    }

    // epilogue: +bias, ->bf16, scatter into q / k / v^T LDS
    for (int a = 0; a < ncnt; ++a) {
      int nt = nt0 + a;
      float bias = bqkv[gcol[a]];
      #pragma unroll
      for (int m = 0; m < 4; ++m) {
        #pragma unroll
        for (int r = 0; r < 4; ++r) {
          unsigned short us = f2bf(acc[a][m][r] + bias);
          int row = m * 16 + quad * 4 + r;    // token
          if (nt < 2)      qs[row * QK_LD + nt * 16 + l16] = us;
          else if (nt < 4) ks[row * QK_LD + (nt - 2) * 16 + l16] = us;
          else             vT[((nt - 4) * 16 + l16) * VT_LD + row] = us;
        }
      }
    }
    __syncthreads();

    // ---- scores S = q k^T * scale, online full-row softmax (rows 16*wave..) ----
    {
      const int mb = wave * 16;
      short8 aq = *reinterpret_cast<const short8*>(&qs[(mb + l16) * QK_LD + quad * 8]);
      floatx4 sacc[4];
      #pragma unroll
      for (int j = 0; j < 4; ++j) {
        short8 bk = *reinterpret_cast<const short8*>(&ks[(j * 16 + l16) * QK_LD + quad * 8]);
        sacc[j] = __builtin_amdgcn_mfma_f32_16x16x32_bf16(aq, bk, zero4, 0, 0, 0);
      }
      const float scale = 0.17677669529663687f;
      #pragma unroll
      for (int r = 0; r < 4; ++r) {
        float s0 = sacc[0][r] * scale, s1 = sacc[1][r] * scale;
        float s2 = sacc[2][r] * scale, s3 = sacc[3][r] * scale;
        float mx = fmaxf(fmaxf(s0, s1), fmaxf(s2, s3));
        #pragma unroll
        for (int off = 1; off < 16; off <<= 1) mx = fmaxf(mx, __shfl_xor(mx, off, 64));
        float e0 = __expf(s0 - mx), e1 = __expf(s1 - mx);
        float e2 = __expf(s2 - mx), e3 = __expf(s3 - mx);
        float sm = e0 + e1 + e2 + e3;
        #pragma unroll
        for (int off = 1; off < 16; off <<= 1) sm += __shfl_xor(sm, off, 64);
        float inv = 1.0f / sm;
        int row = mb + quad * 4 + r;
        ps[row * P_LD +  0 + l16] = f2bf(e0 * inv);
        ps[row * P_LD + 16 + l16] = f2bf(e1 * inv);
        ps[row * P_LD + 32 + l16] = f2bf(e2 * inv);
        ps[row * P_LD + 48 + l16] = f2bf(e3 * inv);
      }
    }
    __syncthreads();

    // ---- O = P V  (64x32, K=64), write bf16 to workspace ----
    {
      const int mb = wave * 16;
      floatx4 oacc[2] = {zero4, zero4};
      #pragma unroll
      for (int kk = 0; kk < 2; ++kk) {
        short8 ap = *reinterpret_cast<const short8*>(&ps[(mb + l16) * P_LD + kk * 32 + quad * 8]);
        #pragma unroll
        for (int nv = 0; nv < 2; ++nv) {
          short8 bv = *reinterpret_cast<const short8*>(
              &vT[(nv * 16 + l16) * VT_LD + kk * 32 + quad * 8]);
          oacc[nv] = __builtin_amdgcn_mfma_f32_16x16x32_bf16(ap, bv, oacc[nv], 0, 0, 0);
        }
      }
      #pragma unroll
      for (int nv = 0; nv < 2; ++nv)
        #pragma unroll
        for (int r = 0; r < 4; ++r) {
          int token = mb + quad * 4 + r;
          o_ws[(size_t)(win * 64 + token) * E + h * HD + nv * 16 + l16] = f2bf(oacc[nv][r]);
        }
    }
    __syncthreads();   // protect q/k/v/p LDS reuse by next head
  }
}

// ---------------- kernel 3: out = O @ Wout^T + b, fused window-reverse + roll ----------------
// grid = (784, 3), 256 threads; 128x128 tile, BK=64
__global__ __launch_bounds__(256, 2)
void out_proj(const unsigned short* __restrict__ o_ws,   // [100352][384] bf16
              const unsigned short* __restrict__ wout,   // [384][384] bf16
              const float* __restrict__ bout,            // [384]
              float* __restrict__ out) {                 // [32][3136][384] fp32
  __shared__ unsigned short As[128 * 72];   // 18432 B
  __shared__ unsigned short Bs[128 * 72];   // 18432 B

  const int tid  = threadIdx.x;
  const int wave = tid >> 6, lane = tid & 63;
  const int quad = lane >> 4, l16 = lane & 15;
  const int wm = wave >> 1, wn = wave & 1;
  const int m0 = blockIdx.x * 128, n0 = blockIdx.y * 128;

  const floatx4 zero4 = {0.f, 0.f, 0.f, 0.f};
  floatx4 acc[4][4];
  #pragma unroll
  for (int mt = 0; mt < 4; ++mt)
    #pragma unroll
    for (int nt = 0; nt < 4; ++nt) acc[mt][nt] = zero4;

  for (int kb = 0; kb < 6; ++kb) {
    #pragma unroll
    for (int it = 0; it < 4; ++it) {
      int f = tid + it * 256;       // 0..1023 over 128 rows x 8 (x8 bf16)
      int row = f >> 3, c8 = f & 7;
      *reinterpret_cast<short8*>(&As[row * 72 + c8 * 8]) =
          *reinterpret_cast<const short8*>(o_ws + (size_t)(m0 + row) * E + kb * 64 + c8 * 8);
      *reinterpret_cast<short8*>(&Bs[row * 72 + c8 * 8]) =
          *reinterpret_cast<const short8*>(wout + (size_t)(n0 + row) * E + kb * 64 + c8 * 8);
    }
    __syncthreads();
    #pragma unroll
    for (int kk = 0; kk < 2; ++kk) {
      short8 af[4], bf[4];
      #pragma unroll
      for (int mt = 0; mt < 4; ++mt)
        af[mt] = *reinterpret_cast<const short8*>(
            &As[(wm * 64 + mt * 16 + l16) * 72 + kk * 32 + quad * 8]);
      #pragma unroll
      for (int nt = 0; nt < 4; ++nt)
        bf[nt] = *reinterpret_cast<const short8*>(
            &Bs[(wn * 64 + nt * 16 + l16) * 72 + kk * 32 + quad * 8]);
      #pragma unroll
      for (int mt = 0; mt < 4; ++mt)
        #pragma unroll
        for (int nt = 0; nt < 4; ++nt)
          acc[mt][nt] = __builtin_amdgcn_mfma_f32_16x16x32_bf16(af[mt], bf[nt], acc[mt][nt], 0, 0, 0);
    }
    __syncthreads();
  }

  // epilogue: bias + scatter (window reverse + roll(+4,+4))
  #pragma unroll
  for (int nt = 0; nt < 4; ++nt) {
    int col = n0 + wn * 64 + nt * 16 + l16;
    float bias = bout[col];
    #pragma unroll
    for (int mt = 0; mt < 4; ++mt) {
      #pragma unroll
      for (int r = 0; r < 4; ++r) {
        int m = m0 + wm * 64 + mt * 16 + quad * 4 + r;
        int win = m >> 6, t = m & 63;
        int bb = win / 49, wrem = win % 49;
        int wi = wrem / 7, wj = wrem % 7;
        int ti = t >> 3, tj = t & 7;
        int gi = (wi * 8 + ti + SH) % HW;
        int gj = (wj * 8 + tj + SH) % HW;
        out[(size_t)(bb * 3136 + gi * 56 + gj) * E + col] = acc[mt][nt][r] + bias;
      }
    }
  }
}

extern "C" void kernel_launch(void* const* d_in, const int* in_sizes, int n_in,
                              void* d_out, int out_size, void* d_ws, size_t ws_size,
                              hipStream_t stream) {
  (void)in_sizes; (void)n_in; (void)out_size; (void)ws_size;
  const float* x    = (const float*)d_in[0];
  const float* wqkv = (const float*)d_in[1];
  const float* bqkv = (const float*)d_in[2];
  const float* wout = (const float*)d_in[3];
  const float* bout = (const float*)d_in[4];
  float* out = (float*)d_out;

  unsigned short* wqkv_bf = (unsigned short*)d_ws;                 // 442368 elems
  unsigned short* wout_bf = wqkv_bf + (size_t)E3 * E;              // 147456 elems
  unsigned short* o_ws    = wout_bf + (size_t)E * E;               // 100352*384 elems (~77 MB)

  cast_weights<<<2304, 256, 0, stream>>>(wqkv, wout, wqkv_bf, wout_bf);
  win_attn<<<NWIN, 256, 0, stream>>>(x, wqkv_bf, bqkv, o_ws);
  out_proj<<<dim3(784, 3), 256, 0, stream>>>(o_ws, wout_bf, bout, out);
}

// Round 2
// 626.192 us; speedup vs baseline: 12.4998x; 12.4998x over previous
//
#include <hip/hip_runtime.h>

typedef short short8 __attribute__((ext_vector_type(8)));
typedef float floatx4 __attribute__((ext_vector_type(4)));

#define DI __device__ __forceinline__

constexpr int Bn   = 32;          // batch
constexpr int HW   = 56;          // spatial H == W
constexpr int E    = 384;
constexpr int E3   = 1152;
constexpr int NHd  = 12;
constexpr int HD   = 32;
constexpr int SH   = 4;           // shift
constexpr int T    = 64;          // tokens per window (8x8)
constexpr int NWIN = Bn * 7 * 7;  // 1568 windows
constexpr int MROW = NWIN * T;    // 100352
constexpr int OS   = E3;          // qkv_ws row stride (1152)

DI unsigned short f2bf(float f) {
  unsigned int u = __builtin_bit_cast(unsigned int, f);
  u = u + 0x7FFFu + ((u >> 16) & 1u);   // round-to-nearest-even
  return (unsigned short)(u >> 16);
}

// ---------------- kernel 1: weights fp32 -> bf16 ----------------
__global__ void cast_weights(const float* __restrict__ wqkv,
                             const float* __restrict__ wout,
                             unsigned short* __restrict__ wqkv_bf,
                             unsigned short* __restrict__ wout_bf) {
  int i = blockIdx.x * 256 + threadIdx.x;
  const int n1 = E3 * E;
  const int n2 = E * E;
  if (i < n1) wqkv_bf[i] = f2bf(wqkv[i]);
  else if (i < n1 + n2) wout_bf[i - n1] = f2bf(wout[i - n1]);
}

// ---------------- kernel 2: QKV GEMM ----------------
// C[100352 x 1152] = Xw[100352 x 384] @ Wqkv[1152 x 384]^T + b
// A-tile gathered from fp32 x with fused roll + window partition.
// grid (784, 9), 256 threads, 128x128 tile, BK=64
__global__ __launch_bounds__(256, 2)
void qkv_gemm(const float* __restrict__ x,
              const unsigned short* __restrict__ wqkv,   // [1152][384] bf16
              const float* __restrict__ bqkv,            // [1152]
              unsigned short* __restrict__ qkv) {        // [100352][1152] bf16
  __shared__ unsigned short As[128 * 72];   // 18432 B
  __shared__ unsigned short Bs[128 * 72];   // 18432 B

  const int tid  = threadIdx.x;
  const int wave = tid >> 6, lane = tid & 63;
  const int quad = lane >> 4, l16 = lane & 15;
  const int wm = wave >> 1, wn = wave & 1;
  const int m0 = blockIdx.x * 128, n0 = blockIdx.y * 128;

  const floatx4 zero4 = {0.f, 0.f, 0.f, 0.f};
  floatx4 acc[4][4];
  #pragma unroll
  for (int mt = 0; mt < 4; ++mt)
    #pragma unroll
    for (int nt = 0; nt < 4; ++nt) acc[mt][nt] = zero4;

  for (int kb = 0; kb < 6; ++kb) {
    // ---- A: gather 128 rows x 64 k-cols from x (roll + window partition), fp32->bf16 ----
    #pragma unroll
    for (int it = 0; it < 8; ++it) {
      int chunk = tid + it * 256;          // 0..2047 over 128 rows x 16 float4
      int row = chunk >> 4, c4 = chunk & 15;
      int m = m0 + row;
      int win = m >> 6, t = m & 63;
      int b = win / 49, wrem = win % 49;
      int wi = wrem / 7, wj = wrem % 7;
      int ti = t >> 3, tj = t & 7;
      int gi = (wi * 8 + ti + SH) % HW;
      int gj = (wj * 8 + tj + SH) % HW;
      const float4 v = *reinterpret_cast<const float4*>(
          x + (size_t)(b * 3136 + gi * 56 + gj) * E + kb * 64 + c4 * 4);
      ushort4 hv;
      hv.x = f2bf(v.x); hv.y = f2bf(v.y); hv.z = f2bf(v.z); hv.w = f2bf(v.w);
      *reinterpret_cast<ushort4*>(&As[row * 72 + c4 * 4]) = hv;
    }
    // ---- B: 128 weight rows x 64 k-cols (bf16, vectorized) ----
    #pragma unroll
    for (int it = 0; it < 4; ++it) {
      int f = tid + it * 256;              // 0..1023 over 128 rows x 8 short8
      int row = f >> 3, c8 = f & 7;
      *reinterpret_cast<short8*>(&Bs[row * 72 + c8 * 8]) =
          *reinterpret_cast<const short8*>(wqkv + (size_t)(n0 + row) * E + kb * 64 + c8 * 8);
    }
    __syncthreads();
    #pragma unroll
    for (int kk = 0; kk < 2; ++kk) {
      short8 af[4], bf[4];
      #pragma unroll
      for (int mt = 0; mt < 4; ++mt)
        af[mt] = *reinterpret_cast<const short8*>(
            &As[(wm * 64 + mt * 16 + l16) * 72 + kk * 32 + quad * 8]);
      #pragma unroll
      for (int nt = 0; nt < 4; ++nt)
        bf[nt] = *reinterpret_cast<const short8*>(
            &Bs[(wn * 64 + nt * 16 + l16) * 72 + kk * 32 + quad * 8]);
      #pragma unroll
      for (int mt = 0; mt < 4; ++mt)
        #pragma unroll
        for (int nt = 0; nt < 4; ++nt)
          acc[mt][nt] = __builtin_amdgcn_mfma_f32_16x16x32_bf16(af[mt], bf[nt], acc[mt][nt], 0, 0, 0);
    }
    __syncthreads();
  }

  // epilogue: +bias, bf16, store
  #pragma unroll
  for (int nt = 0; nt < 4; ++nt) {
    int col = n0 + wn * 64 + nt * 16 + l16;
    float bias = bqkv[col];
    #pragma unroll
    for (int mt = 0; mt < 4; ++mt) {
      #pragma unroll
      for (int r = 0; r < 4; ++r) {
        int m = m0 + wm * 64 + mt * 16 + quad * 4 + r;
        qkv[(size_t)m * OS + col] = f2bf(acc[mt][nt][r] + bias);
      }
    }
  }
}

// ---------------- kernel 3: per-(window,head) attention ----------------
// grid = 1568*12 blocks of 64 threads (one wave). O overwrites the q-columns
// of qkv (disjoint per head; all global reads precede writes).
__global__ __launch_bounds__(64)
void attn(unsigned short* __restrict__ qkv) {
  __shared__ unsigned short qs[T * 40];    // 5120 B
  __shared__ unsigned short ks[T * 40];    // 5120 B
  __shared__ unsigned short vT[HD * 72];   // 4608 B
  __shared__ unsigned short ps[T * 72];    // 9216 B

  const int lane = threadIdx.x;
  const int quad = lane >> 4, l16 = lane & 15;
  const int wh  = blockIdx.x;
  const int win = wh / NHd, h = wh % NHd;
  const size_t base = (size_t)win * T * OS;
  const int hoff = h * HD;

  // ---- stage q, k (64 rows x 32 cols bf16 each) and v^T ----
  #pragma unroll
  for (int it = 0; it < 4; ++it) {
    int c = it * 64 + lane;                // 0..255: 64 rows x 4 short8
    int row = c >> 2, cc = c & 3;
    size_t roff = base + (size_t)row * OS + hoff + cc * 8;
    *reinterpret_cast<short8*>(&qs[row * 40 + cc * 8]) =
        *reinterpret_cast<const short8*>(qkv + roff);
    *reinterpret_cast<short8*>(&ks[row * 40 + cc * 8]) =
        *reinterpret_cast<const short8*>(qkv + roff + E);
  }
  #pragma unroll
  for (int it = 0; it < 4; ++it) {
    int c = it * 64 + lane;
    int t = c >> 2, dc = c & 3;
    short8 vv = *reinterpret_cast<const short8*>(
        qkv + base + (size_t)t * OS + 2 * E + hoff + dc * 8);
    #pragma unroll
    for (int j = 0; j < 8; ++j) vT[(dc * 8 + j) * 72 + t] = (unsigned short)vv[j];
  }
  __syncthreads();

  const floatx4 zero4 = {0.f, 0.f, 0.f, 0.f};

  // ---- S = q k^T (64x64, K=32): 16 MFMAs ----
  short8 aq[4];
  #pragma unroll
  for (int mt = 0; mt < 4; ++mt)
    aq[mt] = *reinterpret_cast<const short8*>(&qs[(mt * 16 + l16) * 40 + quad * 8]);
  floatx4 sacc[4][4];
  #pragma unroll
  for (int nt = 0; nt < 4; ++nt) {
    short8 bk = *reinterpret_cast<const short8*>(&ks[(nt * 16 + l16) * 40 + quad * 8]);
    #pragma unroll
    for (int mt = 0; mt < 4; ++mt)
      sacc[mt][nt] = __builtin_amdgcn_mfma_f32_16x16x32_bf16(aq[mt], bk, zero4, 0, 0, 0);
  }

  // ---- row softmax (each lane owns 16 rows worth: 4 mt x 4 r), P -> LDS bf16 ----
  const float scale = 0.17677669529663687f;
  #pragma unroll
  for (int mt = 0; mt < 4; ++mt) {
    #pragma unroll
    for (int r = 0; r < 4; ++r) {
      float s0 = sacc[mt][0][r] * scale, s1 = sacc[mt][1][r] * scale;
      float s2 = sacc[mt][2][r] * scale, s3 = sacc[mt][3][r] * scale;
      float mx = fmaxf(fmaxf(s0, s1), fmaxf(s2, s3));
      #pragma unroll
      for (int off = 1; off < 16; off <<= 1) mx = fmaxf(mx, __shfl_xor(mx, off, 64));
      float e0 = __expf(s0 - mx), e1 = __expf(s1 - mx);
      float e2 = __expf(s2 - mx), e3 = __expf(s3 - mx);
      float sm = e0 + e1 + e2 + e3;
      #pragma unroll
      for (int off = 1; off < 16; off <<= 1) sm += __shfl_xor(sm, off, 64);
      float inv = 1.0f / sm;
      int row = mt * 16 + quad * 4 + r;
      ps[row * 72 +  0 + l16] = f2bf(e0 * inv);
      ps[row * 72 + 16 + l16] = f2bf(e1 * inv);
      ps[row * 72 + 32 + l16] = f2bf(e2 * inv);
      ps[row * 72 + 48 + l16] = f2bf(e3 * inv);
    }
  }
  __syncthreads();

  // ---- O = P V (64x32, K=64): 16 MFMAs; write into q-columns of qkv ----
  #pragma unroll
  for (int mt = 0; mt < 4; ++mt) {
    floatx4 o0 = zero4, o1 = zero4;
    #pragma unroll
    for (int kk = 0; kk < 2; ++kk) {
      short8 ap = *reinterpret_cast<const short8*>(&ps[(mt * 16 + l16) * 72 + kk * 32 + quad * 8]);
      short8 b0 = *reinterpret_cast<const short8*>(&vT[(l16) * 72 + kk * 32 + quad * 8]);
      short8 b1 = *reinterpret_cast<const short8*>(&vT[(16 + l16) * 72 + kk * 32 + quad * 8]);
      o0 = __builtin_amdgcn_mfma_f32_16x16x32_bf16(ap, b0, o0, 0, 0, 0);
      o1 = __builtin_amdgcn_mfma_f32_16x16x32_bf16(ap, b1, o1, 0, 0, 0);
    }
    #pragma unroll
    for (int r = 0; r < 4; ++r) {
      int tok = mt * 16 + quad * 4 + r;
      qkv[base + (size_t)tok * OS + hoff + l16]      = f2bf(o0[r]);
      qkv[base + (size_t)tok * OS + hoff + 16 + l16] = f2bf(o1[r]);
    }
  }
}

// ---------------- kernel 4: out = O @ Wout^T + b, fused window-reverse + roll ----------------
// O lives in qkv's q-columns (row stride 1152, cols 0..383). grid (784, 3).
__global__ __launch_bounds__(256, 2)
void out_proj(const unsigned short* __restrict__ o_ws,   // [100352][1152] bf16, cols 0..383
              const unsigned short* __restrict__ wout,   // [384][384] bf16
              const float* __restrict__ bout,            // [384]
              float* __restrict__ out) {                 // [32][3136][384] fp32
  __shared__ unsigned short As[128 * 72];
  __shared__ unsigned short Bs[128 * 72];

  const int tid  = threadIdx.x;
  const int wave = tid >> 6, lane = tid & 63;
  const int quad = lane >> 4, l16 = lane & 15;
  const int wm = wave >> 1, wn = wave & 1;
  const int m0 = blockIdx.x * 128, n0 = blockIdx.y * 128;

  const floatx4 zero4 = {0.f, 0.f, 0.f, 0.f};
  floatx4 acc[4][4];
  #pragma unroll
  for (int mt = 0; mt < 4; ++mt)
    #pragma unroll
    for (int nt = 0; nt < 4; ++nt) acc[mt][nt] = zero4;

  for (int kb = 0; kb < 6; ++kb) {
    #pragma unroll
    for (int it = 0; it < 4; ++it) {
      int f = tid + it * 256;
      int row = f >> 3, c8 = f & 7;
      *reinterpret_cast<short8*>(&As[row * 72 + c8 * 8]) =
          *reinterpret_cast<const short8*>(o_ws + (size_t)(m0 + row) * OS + kb * 64 + c8 * 8);
      *reinterpret_cast<short8*>(&Bs[row * 72 + c8 * 8]) =
          *reinterpret_cast<const short8*>(wout + (size_t)(n0 + row) * E + kb * 64 + c8 * 8);
    }
    __syncthreads();
    #pragma unroll
    for (int kk = 0; kk < 2; ++kk) {
      short8 af[4], bf[4];
      #pragma unroll
      for (int mt = 0; mt < 4; ++mt)
        af[mt] = *reinterpret_cast<const short8*>(
            &As[(wm * 64 + mt * 16 + l16) * 72 + kk * 32 + quad * 8]);
      #pragma unroll
      for (int nt = 0; nt < 4; ++nt)
        bf[nt] = *reinterpret_cast<const short8*>(
            &Bs[(wn * 64 + nt * 16 + l16) * 72 + kk * 32 + quad * 8]);
      #pragma unroll
      for (int mt = 0; mt < 4; ++mt)
        #pragma unroll
        for (int nt = 0; nt < 4; ++nt)
          acc[mt][nt] = __builtin_amdgcn_mfma_f32_16x16x32_bf16(af[mt], bf[nt], acc[mt][nt], 0, 0, 0);
    }
    __syncthreads();
  }

  #pragma unroll
  for (int nt = 0; nt < 4; ++nt) {
    int col = n0 + wn * 64 + nt * 16 + l16;
    float bias = bout[col];
    #pragma unroll
    for (int mt = 0; mt < 4; ++mt) {
      #pragma unroll
      for (int r = 0; r < 4; ++r) {
        int m = m0 + wm * 64 + mt * 16 + quad * 4 + r;
        int win = m >> 6, t = m & 63;
        int bb = win / 49, wrem = win % 49;
        int wi = wrem / 7, wj = wrem % 7;
        int ti = t >> 3, tj = t & 7;
        int gi = (wi * 8 + ti + SH) % HW;
        int gj = (wj * 8 + tj + SH) % HW;
        out[(size_t)(bb * 3136 + gi * 56 + gj) * E + col] = acc[mt][nt][r] + bias;
      }
    }
  }
}

extern "C" void kernel_launch(void* const* d_in, const int* in_sizes, int n_in,
                              void* d_out, int out_size, void* d_ws, size_t ws_size,
                              hipStream_t stream) {
  (void)in_sizes; (void)n_in; (void)out_size; (void)ws_size;
  const float* x    = (const float*)d_in[0];
  const float* wqkv = (const float*)d_in[1];
  const float* bqkv = (const float*)d_in[2];
  const float* wout = (const float*)d_in[3];
  const float* bout = (const float*)d_in[4];
  float* out = (float*)d_out;

  unsigned short* wqkv_bf = (unsigned short*)d_ws;                 // 442368 elems
  unsigned short* wout_bf = wqkv_bf + (size_t)E3 * E;              // 147456 elems
  unsigned short* qkv_ws  = wout_bf + (size_t)E * E;               // 100352*1152 elems (~231 MB)

  cast_weights<<<2304, 256, 0, stream>>>(wqkv, wout, wqkv_bf, wout_bf);
  qkv_gemm<<<dim3(784, 9), 256, 0, stream>>>(x, wqkv_bf, bqkv, qkv_ws);
  attn<<<NWIN * NHd, 64, 0, stream>>>(qkv_ws);
  out_proj<<<dim3(784, 3), 256, 0, stream>>>(qkv_ws, wout_bf, bout, out);
}

// Round 3
// 607.058 us; speedup vs baseline: 12.8938x; 1.0315x over previous
//
#include <hip/hip_runtime.h>

typedef short short8 __attribute__((ext_vector_type(8)));
typedef float floatx4 __attribute__((ext_vector_type(4)));

#define DI __device__ __forceinline__

constexpr int Bn   = 32;          // batch
constexpr int HW   = 56;          // spatial H == W
constexpr int E    = 384;
constexpr int E3   = 1152;
constexpr int NHd  = 12;
constexpr int HD   = 32;
constexpr int SH   = 4;           // shift
constexpr int T    = 64;          // tokens per window (8x8)
constexpr int NWIN = Bn * 7 * 7;  // 1568 windows
constexpr int MROW = NWIN * T;    // 100352
constexpr int OS   = E3;          // qkv_ws row stride (1152)

DI unsigned short f2bf(float f) {
  unsigned int u = __builtin_bit_cast(unsigned int, f);
  u = u + 0x7FFFu + ((u >> 16) & 1u);   // round-to-nearest-even
  return (unsigned short)(u >> 16);
}

// ---------------- kernel 1: weights fp32 -> bf16 ----------------
__global__ void cast_weights(const float* __restrict__ wqkv,
                             const float* __restrict__ wout,
                             unsigned short* __restrict__ wqkv_bf,
                             unsigned short* __restrict__ wout_bf) {
  int i = blockIdx.x * 256 + threadIdx.x;
  const int n1 = E3 * E;
  const int n2 = E * E;
  if (i < n1) wqkv_bf[i] = f2bf(wqkv[i]);
  else if (i < n1 + n2) wout_bf[i - n1] = f2bf(wout[i - n1]);
}

// ---------------- kernel 2: QKV GEMM ----------------
// C[100352 x 1152] = Xw[100352 x 384] @ Wqkv[1152 x 384]^T + b
// grid (9, 784): n-tile fastest so the 9 blocks sharing one A-panel are
// dispatch-adjacent (A read once from HBM, reused via L2/L3).
__global__ __launch_bounds__(256, 2)
void qkv_gemm(const float* __restrict__ x,
              const unsigned short* __restrict__ wqkv,   // [1152][384] bf16
              const float* __restrict__ bqkv,            // [1152]
              unsigned short* __restrict__ qkv) {        // [100352][1152] bf16
  __shared__ unsigned short As[128 * 72];   // 18432 B
  __shared__ unsigned short Bs[128 * 72];   // 18432 B

  const int tid  = threadIdx.x;
  const int wave = tid >> 6, lane = tid & 63;
  const int quad = lane >> 4, l16 = lane & 15;
  const int wm = wave >> 1, wn = wave & 1;
  const int m0 = blockIdx.y * 128, n0 = blockIdx.x * 128;

  // hoisted A-gather source pointers (roll + window partition), constant over kb
  const float* asrc[8];
  int adst[8];
  #pragma unroll
  for (int it = 0; it < 8; ++it) {
    int chunk = tid + it * 256;          // 0..2047 over 128 rows x 16 float4
    int row = chunk >> 4, c4 = chunk & 15;
    int m = m0 + row;
    int win = m >> 6, t = m & 63;
    int b = win / 49, wrem = win % 49;
    int wi = wrem / 7, wj = wrem % 7;
    int ti = t >> 3, tj = t & 7;
    int gi = (wi * 8 + ti + SH) % HW;
    int gj = (wj * 8 + tj + SH) % HW;
    asrc[it] = x + (size_t)(b * 3136 + gi * 56 + gj) * E + c4 * 4;
    adst[it] = row * 72 + c4 * 4;
  }

  const floatx4 zero4 = {0.f, 0.f, 0.f, 0.f};
  floatx4 acc[4][4];
  #pragma unroll
  for (int mt = 0; mt < 4; ++mt)
    #pragma unroll
    for (int nt = 0; nt < 4; ++nt) acc[mt][nt] = zero4;

  for (int kb = 0; kb < 6; ++kb) {
    #pragma unroll
    for (int it = 0; it < 8; ++it) {
      const float4 v = *reinterpret_cast<const float4*>(asrc[it] + kb * 64);
      ushort4 hv;
      hv.x = f2bf(v.x); hv.y = f2bf(v.y); hv.z = f2bf(v.z); hv.w = f2bf(v.w);
      *reinterpret_cast<ushort4*>(&As[adst[it]]) = hv;
    }
    #pragma unroll
    for (int it = 0; it < 4; ++it) {
      int f = tid + it * 256;              // 0..1023 over 128 rows x 8 short8
      int row = f >> 3, c8 = f & 7;
      *reinterpret_cast<short8*>(&Bs[row * 72 + c8 * 8]) =
          *reinterpret_cast<const short8*>(wqkv + (size_t)(n0 + row) * E + kb * 64 + c8 * 8);
    }
    __syncthreads();
    #pragma unroll
    for (int kk = 0; kk < 2; ++kk) {
      short8 af[4], bf[4];
      #pragma unroll
      for (int mt = 0; mt < 4; ++mt)
        af[mt] = *reinterpret_cast<const short8*>(
            &As[(wm * 64 + mt * 16 + l16) * 72 + kk * 32 + quad * 8]);
      #pragma unroll
      for (int nt = 0; nt < 4; ++nt)
        bf[nt] = *reinterpret_cast<const short8*>(
            &Bs[(wn * 64 + nt * 16 + l16) * 72 + kk * 32 + quad * 8]);
      #pragma unroll
      for (int mt = 0; mt < 4; ++mt)
        #pragma unroll
        for (int nt = 0; nt < 4; ++nt)
          acc[mt][nt] = __builtin_amdgcn_mfma_f32_16x16x32_bf16(af[mt], bf[nt], acc[mt][nt], 0, 0, 0);
    }
    __syncthreads();
  }

  // epilogue: +bias, bf16, store
  #pragma unroll
  for (int nt = 0; nt < 4; ++nt) {
    int col = n0 + wn * 64 + nt * 16 + l16;
    float bias = bqkv[col];
    #pragma unroll
    for (int mt = 0; mt < 4; ++mt) {
      #pragma unroll
      for (int r = 0; r < 4; ++r) {
        int m = m0 + wm * 64 + mt * 16 + quad * 4 + r;
        qkv[(size_t)m * OS + col] = f2bf(acc[mt][nt][r] + bias);
      }
    }
  }
}

// ---------------- kernel 3: per-(window,head) attention ----------------
// grid = 1568*12 blocks of 64 threads (one wave). O overwrites the q-columns
// of qkv (disjoint per head; all global reads precede writes).
// LDS aliasing: ps (64x72) reuses the q/k region (dead after S=QK^T).
__global__ __launch_bounds__(64)
void attn(unsigned short* __restrict__ qkv) {
  __shared__ unsigned short smem[7424];   // 14848 B
  unsigned short* qs = smem;              // 64 x 40 = 2560
  unsigned short* ks = smem + 2560;       // 64 x 40 = 2560
  unsigned short* ps = smem;              // 64 x 72 = 4608 (aliases qs/ks)
  unsigned short* vT = smem + 5120;       // 32 x 72 = 2304

  const int lane = threadIdx.x;
  const int quad = lane >> 4, l16 = lane & 15;
  const int wh  = blockIdx.x;
  const int win = wh / NHd, h = wh % NHd;
  const size_t base = (size_t)win * T * OS;
  const int hoff = h * HD;

  // ---- stage q, k (64 rows x 32 cols bf16 each) and v^T ----
  #pragma unroll
  for (int it = 0; it < 4; ++it) {
    int c = it * 64 + lane;                // 0..255: 64 rows x 4 short8
    int row = c >> 2, cc = c & 3;
    size_t roff = base + (size_t)row * OS + hoff + cc * 8;
    *reinterpret_cast<short8*>(&qs[row * 40 + cc * 8]) =
        *reinterpret_cast<const short8*>(qkv + roff);
    *reinterpret_cast<short8*>(&ks[row * 40 + cc * 8]) =
        *reinterpret_cast<const short8*>(qkv + roff + E);
  }
  #pragma unroll
  for (int it = 0; it < 4; ++it) {
    int c = it * 64 + lane;
    int t = c >> 2, dc = c & 3;
    short8 vv = *reinterpret_cast<const short8*>(
        qkv + base + (size_t)t * OS + 2 * E + hoff + dc * 8);
    #pragma unroll
    for (int j = 0; j < 8; ++j) vT[(dc * 8 + j) * 72 + t] = (unsigned short)vv[j];
  }
  __syncthreads();

  const floatx4 zero4 = {0.f, 0.f, 0.f, 0.f};

  // ---- S = q k^T (64x64, K=32): 16 MFMAs ----
  short8 aq[4];
  #pragma unroll
  for (int mt = 0; mt < 4; ++mt)
    aq[mt] = *reinterpret_cast<const short8*>(&qs[(mt * 16 + l16) * 40 + quad * 8]);
  floatx4 sacc[4][4];
  #pragma unroll
  for (int nt = 0; nt < 4; ++nt) {
    short8 bk = *reinterpret_cast<const short8*>(&ks[(nt * 16 + l16) * 40 + quad * 8]);
    #pragma unroll
    for (int mt = 0; mt < 4; ++mt)
      sacc[mt][nt] = __builtin_amdgcn_mfma_f32_16x16x32_bf16(aq[mt], bk, zero4, 0, 0, 0);
  }
  __syncthreads();   // q/k LDS dead; ps aliases it

  // ---- row softmax, P -> LDS bf16 ----
  const float scale = 0.17677669529663687f;
  #pragma unroll
  for (int mt = 0; mt < 4; ++mt) {
    #pragma unroll
    for (int r = 0; r < 4; ++r) {
      float s0 = sacc[mt][0][r] * scale, s1 = sacc[mt][1][r] * scale;
      float s2 = sacc[mt][2][r] * scale, s3 = sacc[mt][3][r] * scale;
      float mx = fmaxf(fmaxf(s0, s1), fmaxf(s2, s3));
      #pragma unroll
      for (int off = 1; off < 16; off <<= 1) mx = fmaxf(mx, __shfl_xor(mx, off, 64));
      float e0 = __expf(s0 - mx), e1 = __expf(s1 - mx);
      float e2 = __expf(s2 - mx), e3 = __expf(s3 - mx);
      float sm = e0 + e1 + e2 + e3;
      #pragma unroll
      for (int off = 1; off < 16; off <<= 1) sm += __shfl_xor(sm, off, 64);
      float inv = 1.0f / sm;
      int row = mt * 16 + quad * 4 + r;
      ps[row * 72 +  0 + l16] = f2bf(e0 * inv);
      ps[row * 72 + 16 + l16] = f2bf(e1 * inv);
      ps[row * 72 + 32 + l16] = f2bf(e2 * inv);
      ps[row * 72 + 48 + l16] = f2bf(e3 * inv);
    }
  }
  __syncthreads();

  // ---- O = P V (64x32, K=64): 16 MFMAs; write into q-columns of qkv ----
  #pragma unroll
  for (int mt = 0; mt < 4; ++mt) {
    floatx4 o0 = zero4, o1 = zero4;
    #pragma unroll
    for (int kk = 0; kk < 2; ++kk) {
      short8 ap = *reinterpret_cast<const short8*>(&ps[(mt * 16 + l16) * 72 + kk * 32 + quad * 8]);
      short8 b0 = *reinterpret_cast<const short8*>(&vT[(l16) * 72 + kk * 32 + quad * 8]);
      short8 b1 = *reinterpret_cast<const short8*>(&vT[(16 + l16) * 72 + kk * 32 + quad * 8]);
      o0 = __builtin_amdgcn_mfma_f32_16x16x32_bf16(ap, b0, o0, 0, 0, 0);
      o1 = __builtin_amdgcn_mfma_f32_16x16x32_bf16(ap, b1, o1, 0, 0, 0);
    }
    #pragma unroll
    for (int r = 0; r < 4; ++r) {
      int tok = mt * 16 + quad * 4 + r;
      qkv[base + (size_t)tok * OS + hoff + l16]      = f2bf(o0[r]);
      qkv[base + (size_t)tok * OS + hoff + 16 + l16] = f2bf(o1[r]);
    }
  }
}

// ---------------- kernel 4: out = O @ Wout^T + b, fused window-reverse + roll ----------------
// O lives in qkv's q-columns (row stride 1152, cols 0..383). grid (3, 784).
__global__ __launch_bounds__(256, 2)
void out_proj(const unsigned short* __restrict__ o_ws,   // [100352][1152] bf16, cols 0..383
              const unsigned short* __restrict__ wout,   // [384][384] bf16
              const float* __restrict__ bout,            // [384]
              float* __restrict__ out) {                 // [32][3136][384] fp32
  __shared__ unsigned short As[128 * 72];
  __shared__ unsigned short Bs[128 * 72];

  const int tid  = threadIdx.x;
  const int wave = tid >> 6, lane = tid & 63;
  const int quad = lane >> 4, l16 = lane & 15;
  const int wm = wave >> 1, wn = wave & 1;
  const int m0 = blockIdx.y * 128, n0 = blockIdx.x * 128;

  const floatx4 zero4 = {0.f, 0.f, 0.f, 0.f};
  floatx4 acc[4][4];
  #pragma unroll
  for (int mt = 0; mt < 4; ++mt)
    #pragma unroll
    for (int nt = 0; nt < 4; ++nt) acc[mt][nt] = zero4;

  for (int kb = 0; kb < 6; ++kb) {
    #pragma unroll
    for (int it = 0; it < 4; ++it) {
      int f = tid + it * 256;
      int row = f >> 3, c8 = f & 7;
      *reinterpret_cast<short8*>(&As[row * 72 + c8 * 8]) =
          *reinterpret_cast<const short8*>(o_ws + (size_t)(m0 + row) * OS + kb * 64 + c8 * 8);
      *reinterpret_cast<short8*>(&Bs[row * 72 + c8 * 8]) =
          *reinterpret_cast<const short8*>(wout + (size_t)(n0 + row) * E + kb * 64 + c8 * 8);
    }
    __syncthreads();
    #pragma unroll
    for (int kk = 0; kk < 2; ++kk) {
      short8 af[4], bf[4];
      #pragma unroll
      for (int mt = 0; mt < 4; ++mt)
        af[mt] = *reinterpret_cast<const short8*>(
            &As[(wm * 64 + mt * 16 + l16) * 72 + kk * 32 + quad * 8]);
      #pragma unroll
      for (int nt = 0; nt < 4; ++nt)
        bf[nt] = *reinterpret_cast<const short8*>(
            &Bs[(wn * 64 + nt * 16 + l16) * 72 + kk * 32 + quad * 8]);
      #pragma unroll
      for (int mt = 0; mt < 4; ++mt)
        #pragma unroll
        for (int nt = 0; nt < 4; ++nt)
          acc[mt][nt] = __builtin_amdgcn_mfma_f32_16x16x32_bf16(af[mt], bf[nt], acc[mt][nt], 0, 0, 0);
    }
    __syncthreads();
  }

  #pragma unroll
  for (int nt = 0; nt < 4; ++nt) {
    int col = n0 + wn * 64 + nt * 16 + l16;
    float bias = bout[col];
    #pragma unroll
    for (int mt = 0; mt < 4; ++mt) {
      #pragma unroll
      for (int r = 0; r < 4; ++r) {
        int m = m0 + wm * 64 + mt * 16 + quad * 4 + r;
        int win = m >> 6, t = m & 63;
        int bb = win / 49, wrem = win % 49;
        int wi = wrem / 7, wj = wrem % 7;
        int ti = t >> 3, tj = t & 7;
        int gi = (wi * 8 + ti + SH) % HW;
        int gj = (wj * 8 + tj + SH) % HW;
        out[(size_t)(bb * 3136 + gi * 56 + gj) * E + col] = acc[mt][nt][r] + bias;
      }
    }
  }
}

extern "C" void kernel_launch(void* const* d_in, const int* in_sizes, int n_in,
                              void* d_out, int out_size, void* d_ws, size_t ws_size,
                              hipStream_t stream) {
  (void)in_sizes; (void)n_in; (void)out_size; (void)ws_size;
  const float* x    = (const float*)d_in[0];
  const float* wqkv = (const float*)d_in[1];
  const float* bqkv = (const float*)d_in[2];
  const float* wout = (const float*)d_in[3];
  const float* bout = (const float*)d_in[4];
  float* out = (float*)d_out;

  unsigned short* wqkv_bf = (unsigned short*)d_ws;                 // 442368 elems
  unsigned short* wout_bf = wqkv_bf + (size_t)E3 * E;              // 147456 elems
  unsigned short* qkv_ws  = wout_bf + (size_t)E * E;               // 100352*1152 elems (~231 MB)

  cast_weights<<<2304, 256, 0, stream>>>(wqkv, wout, wqkv_bf, wout_bf);
  qkv_gemm<<<dim3(9, 784), 256, 0, stream>>>(x, wqkv_bf, bqkv, qkv_ws);
  attn<<<NWIN * NHd, 64, 0, stream>>>(qkv_ws);
  out_proj<<<dim3(3, 784), 256, 0, stream>>>(qkv_ws, wout_bf, bout, out);
}